// Round 9
// baseline (118.996 us; speedup 1.0000x reference)
//
#include <hip/hip_runtime.h>
#include <math.h>

#define BB 128
#define SS 1024
#define DD 256
#define NP (BB * SS)      // 131072 points
#define CH 16             // S-chunks per b in K1
#define ROWS (SS / CH)    // 64 rows per chunk
#define NB3 2048          // blocks for the two big sweep kernels
#define NW3 (NB3 * 4)     // 8192 waves
#define RB4 32            // part3 rows per K4a block
#define NB4A (NB3 / RB4)  // 64 blocks in K4a

// ---- fast HW transcendentals (v_exp_f32 is exp2, v_log_f32 is log2) ----
#define LN2F 0.69314718056f
#define L2EF 1.44269504089f
__device__ __forceinline__ float fsqrt(float x) { return __builtin_amdgcn_sqrtf(x); }
__device__ __forceinline__ float frcp(float x)  { return __builtin_amdgcn_rcpf(x); }
__device__ __forceinline__ float frsq(float x)  { return __builtin_amdgcn_rsqf(x); }
__device__ __forceinline__ float flog2(float x) { return __builtin_amdgcn_logf(x); }
__device__ __forceinline__ float fexp2(float x) { return __builtin_amdgcn_exp2f(x); }

// ---- wave (64-lane) sum via xor shuffle ----
__device__ __forceinline__ float wave_sum(float v) {
#pragma unroll
    for (int m = 32; m >= 1; m >>= 1) v += __shfl_xor(v, m, 64);
    return v;
}

// ---- wave sum of TWO independent values, interleaved for ILP ----
__device__ __forceinline__ void wave_sum2(float& a, float& b) {
#pragma unroll
    for (int m = 32; m >= 1; m >>= 1) {
        float ta = __shfl_xor(a, m, 64);
        float tb = __shfl_xor(b, m, 64);
        a += ta;
        b += tb;
    }
}

// ---- block (256-thread) tree sum; result broadcast to all threads ----
__device__ __forceinline__ float block_sum(float v, float* red) {
    const int t = threadIdx.x;
    red[t] = v;
    __syncthreads();
#pragma unroll
    for (int off = 128; off >= 1; off >>= 1) {
        if (t < off) red[t] += red[t + off];
        __syncthreads();
    }
    float r = red[0];
    __syncthreads();
    return r;
}

__device__ __forceinline__ float dot4(float4 a, float4 b) {
    return fmaf(a.x, b.x, fmaf(a.y, b.y, fmaf(a.z, b.z, a.w * b.w)));
}

// ---- per-block prologue: recompute mean[256] from c1 into LDS (identical in all blocks) ----
__device__ __forceinline__ void mean_prologue(const float* __restrict__ c1,
                                              float* mean_lds, float* red) {
    const int t = threadIdx.x;
    float acc = 0.f;
#pragma unroll 8
    for (int b = 0; b < BB; ++b) acc += c1[(size_t)b * DD + t];
    float avg = acc * (1.0f / BB);
    float contrib = (t == 0) ? avg * avg : -avg * avg;
    float r = block_sum(contrib, red);
    mean_lds[t] = avg * frsq(fmaxf(fabsf(r), 1e-8f));
    __syncthreads();
}

// K1: partial sums over S-chunks: part[b][ch][d] = sum_{s in chunk} x[b,s,d]
__global__ __launch_bounds__(256) void k1_partial(const float* __restrict__ x,
                                                  float* __restrict__ part) {
    const int ch = blockIdx.x, b = blockIdx.y;
    const int w = threadIdx.x >> 6, l = threadIdx.x & 63;
    const float4* x4 = (const float4*)x;
    size_t base = ((size_t)b * SS + (size_t)ch * ROWS + (size_t)w * (ROWS / 4)) * (DD / 4);
    float4 s = make_float4(0.f, 0.f, 0.f, 0.f);
#pragma unroll 4
    for (int r = 0; r < ROWS / 4; ++r) {
        float4 v = x4[base + (size_t)r * (DD / 4) + l];
        s.x += v.x; s.y += v.y; s.z += v.z; s.w += v.w;
    }
    __shared__ float lds[4][DD];
    lds[w][4 * l + 0] = s.x; lds[w][4 * l + 1] = s.y;
    lds[w][4 * l + 2] = s.z; lds[w][4 * l + 3] = s.w;
    __syncthreads();
    const int t = threadIdx.x;
    part[((size_t)b * CH + ch) * DD + t] = lds[0][t] + lds[1][t] + lds[2][t] + lds[3][t];
}

// K2a: per-b Lorentz centroid over S: c1[b][d]
__global__ __launch_bounds__(256) void k2a_c1(const float* __restrict__ part,
                                              float* __restrict__ c1) {
    const int b = blockIdx.x;
    const int t = threadIdx.x;
    __shared__ float red[DD];
    float sx = 0.f;
#pragma unroll
    for (int ch = 0; ch < CH; ++ch) sx += part[((size_t)b * CH + ch) * DD + t];
    float avg = sx * (1.0f / SS);
    float contrib = (t == 0) ? avg * avg : -avg * avg;
    float r = block_sum(contrib, red);
    c1[(size_t)b * DD + t] = avg * frsq(fmaxf(fabsf(r), 1e-8f));
}

// x_t' = transp0back(mean, logmap(mean, y)) for one point (wave-per-point; lane l owns feats 4l..4l+3)
__device__ __forceinline__ float4 compute_xt(const float4* __restrict__ row, int l,
                                             float4 m4, float m0, float inv1pm0) {
    float4 v = row[l];
    float dp = dot4(v, m4);
    float dot = wave_sum(dp);                 // sum_all mean_i * y_i
    float y0 = __shfl(v.x, 0, 64);            // feature 0
    float alpha = fmaxf(fmaf(2.0f * m0, y0, -dot), 1.0f + 1e-7f);
    float tt = fmaf(alpha, alpha, -1.0f);
    // f = acosh(alpha)/sqrt(alpha^2-1) = ln2*log2(alpha+sqrt(tt)) * rsqrt(tt)
    float f = (LN2F * flog2(alpha + fsqrt(tt))) * frsq(tt);
    float xt0 = f * (y0 - alpha * m0);
    float coef = xt0 * inv1pm0;               // xt0 / (1 + mean0)
    float4 r;
    r.x = f * (v.x - alpha * m4.x) - coef * ((l == 0) ? (m0 + 1.0f) : m4.x);
    r.y = f * (v.y - alpha * m4.y) - coef * m4.y;
    r.z = f * (v.z - alpha * m4.z) - coef * m4.z;
    r.w = f * (v.w - alpha * m4.w) - coef * m4.w;
    return r;
}

// K3: prologue computes mean from c1; then per-feature partial sum/sumsq of x_t'
__global__ __launch_bounds__(256, 8) void k3_stats(const float* __restrict__ x,
                                                   const float* __restrict__ c1,
                                                   float* __restrict__ part3) {
    __shared__ float mean_lds[DD];
    __shared__ float red[DD];
    mean_prologue(c1, mean_lds, red);

    const int w = threadIdx.x >> 6, l = threadIdx.x & 63;
    float4 m4 = ((const float4*)mean_lds)[l];
    float m0 = mean_lds[0];
    float inv1pm0 = frcp(1.0f + m0);
    float4 s = make_float4(0, 0, 0, 0), q = make_float4(0, 0, 0, 0);
    const int wid = blockIdx.x * 4 + w;
#pragma unroll 2
    for (int p = wid; p < NP; p += NW3) {
        const float4* row = ((const float4*)x) + (size_t)p * (DD / 4);
        float4 t4 = compute_xt(row, l, m4, m0, inv1pm0);
        s.x += t4.x; s.y += t4.y; s.z += t4.z; s.w += t4.w;
        q.x += t4.x * t4.x; q.y += t4.y * t4.y; q.z += t4.z * t4.z; q.w += t4.w * t4.w;
    }
    __shared__ float lds[4][2 * DD];
    lds[w][4 * l + 0] = s.x; lds[w][4 * l + 1] = s.y;
    lds[w][4 * l + 2] = s.z; lds[w][4 * l + 3] = s.w;
    lds[w][DD + 4 * l + 0] = q.x; lds[w][DD + 4 * l + 1] = q.y;
    lds[w][DD + 4 * l + 2] = q.z; lds[w][DD + 4 * l + 3] = q.w;
    __syncthreads();
    const int t = threadIdx.x;
    part3[(size_t)blockIdx.x * (2 * DD) + t]      = lds[0][t] + lds[1][t] + lds[2][t] + lds[3][t];
    part3[(size_t)blockIdx.x * (2 * DD) + DD + t] = lds[0][DD + t] + lds[1][DD + t] + lds[2][DD + t] + lds[3][DD + t];
}

// K4a: reduce part3 rows 32-at-a-time -> stage2[64][2*DD]
__global__ __launch_bounds__(512) void k4a_reduce(const float* __restrict__ part3,
                                                  float* __restrict__ stage2) {
    const int t = threadIdx.x;            // column 0..511
    const int r0 = blockIdx.x * RB4;
    float s = 0.f;
#pragma unroll 8
    for (int r = 0; r < RB4; ++r) s += part3[(size_t)(r0 + r) * (2 * DD) + t];
    stage2[(size_t)blockIdx.x * (2 * DD) + t] = s;
}

// K5: prologue computes mean (from c1) and scale (from stage2); then output pass.
//   coef = <beta,v>/(1+b0),  <wv,wv> = <v,v> - 2*coef*v0  (wv = v + coef*(beta+o))
__global__ __launch_bounds__(256, 8) void k5_out(const float* __restrict__ x,
                                                 const float* __restrict__ c1,
                                                 const float* __restrict__ stage2,
                                                 const float* __restrict__ gamma,
                                                 const float* __restrict__ beta,
                                                 float4* __restrict__ out4) {
    __shared__ float mean_lds[DD];
    __shared__ float scale_lds[DD];
    __shared__ float red[DD];
    const int t = threadIdx.x;
    // scale prologue (no cross-thread dep)
    {
        double s1 = 0.0, s2 = 0.0;
#pragma unroll 8
        for (int i = 0; i < NB4A; ++i) {
            s1 += (double)stage2[(size_t)i * (2 * DD) + t];
            s2 += (double)stage2[(size_t)i * (2 * DD) + DD + t];
        }
        const double N = (double)NP;
        double mv = s1 / N;
        double var = s2 / N - mv * mv;
        scale_lds[t] = gamma[0] * frsq((float)var + 1e-5f);
    }
    mean_prologue(c1, mean_lds, red);   // includes final __syncthreads

    const int w = threadIdx.x >> 6, l = threadIdx.x & 63;
    float4 m4 = ((const float4*)mean_lds)[l];
    float m0 = mean_lds[0];
    float inv1pm0 = frcp(1.0f + m0);
    float4 sc = ((const float4*)scale_lds)[l];
    float4 b4 = ((const float4*)beta)[l];
    float b0 = beta[0];
    float inv1pb0 = frcp(1.0f + b0);
    float b0p1 = b0 + 1.0f;
    const int wid = blockIdx.x * 4 + w;
#pragma unroll 2
    for (int p = wid; p < NP; p += NW3) {
        const float4* row = ((const float4*)x) + (size_t)p * (DD / 4);
        float4 t4 = compute_xt(row, l, m4, m0, inv1pm0);
        float4 v = make_float4(t4.x * sc.x, t4.y * sc.y, t4.z * sc.z, t4.w * sc.w);
        float pb = dot4(v, b4);     // -> <beta,v> after v0 correction
        float pv = dot4(v, v);      // -> <v,v>    after v0 correction
        wave_sum2(pb, pv);
        float v0 = __shfl(v.x, 0, 64);
        float coef = fmaf(-2.0f * b0, v0, pb) * inv1pb0;        // <beta,v>_L/(1+b0)
        float vvL = fmaf(-2.0f * v0, v0, pv);                   // <v,v>_L
        float nn = fmaxf(fmaf(-2.0f * coef, v0, vvL), 1e-7f);   // <wv,wv>_L
        float n = fsqrt(nn);
        float e = fexp2(n * L2EF);             // e^n
        float ei = frcp(e);                    // e^-n
        float chn = 0.5f * (e + ei);
        float shn = 0.5f * (e - ei) * frsq(nn);   // sinh(n)/n
        float4 o;
        o.x = fmaf(chn, (l == 0) ? b0 : b4.x,
                   shn * (v.x + coef * ((l == 0) ? b0p1 : b4.x)));
        o.y = fmaf(chn, b4.y, shn * fmaf(coef, b4.y, v.y));
        o.z = fmaf(chn, b4.z, shn * fmaf(coef, b4.z, v.z));
        o.w = fmaf(chn, b4.w, shn * fmaf(coef, b4.w, v.w));
        out4[(size_t)p * (DD / 4) + l] = o;
    }
}

extern "C" void kernel_launch(void* const* d_in, const int* in_sizes, int n_in,
                              void* d_out, int out_size, void* d_ws, size_t ws_size,
                              hipStream_t stream) {
    (void)in_sizes; (void)n_in; (void)out_size; (void)ws_size;
    const float* x     = (const float*)d_in[0];
    const float* beta  = (const float*)d_in[1];
    const float* gamma = (const float*)d_in[2];
    float* out = (float*)d_out;

    // Scratch layout (d_ws, 512 MiB). c1 must survive until K5; part3 may alias part.
    float* scratch = (float*)d_ws;
    float* c1     = scratch;                               // [BB][DD]      =   32768 floats
    float* part   = scratch + 32768;                       // [BB][CH][DD]  =  524288 floats
    float* part3  = scratch + 32768;                       // [NB3][2*DD]   = 1048576 floats (aliases part; part dead after K2a)
    float* stage2 = scratch + 32768 + 1048576;             // [NB4A][2*DD]  =   32768 floats

    k1_partial<<<dim3(CH, BB), 256, 0, stream>>>(x, part);
    k2a_c1<<<BB, 256, 0, stream>>>(part, c1);
    k3_stats<<<NB3, 256, 0, stream>>>(x, c1, part3);
    k4a_reduce<<<NB4A, 512, 0, stream>>>(part3, stage2);
    k5_out<<<NB3, 256, 0, stream>>>(x, c1, stage2, gamma, beta, (float4*)out);
}